// Round 4
// baseline (1963.293 us; speedup 1.0000x reference)
//
#include <hip/hip_runtime.h>
#include <hip/hip_bf16.h>

typedef unsigned short u16;
typedef __attribute__((ext_vector_type(8))) short   short8;
typedef __attribute__((ext_vector_type(8))) __bf16  bf16x8;
typedef __attribute__((ext_vector_type(16))) float  floatx16;

#define DD  128   // D
#define FE  16    // edge feature dim
#define DIN 145   // D + Fe + 1
#define K1  160   // Din padded to multiple of 16
#define K1P 168   // xs LDS row stride (shorts)
#define HQ  256   // hidden width
#define HQP 264   // h1 LDS row stride (shorts)
#define ME  32    // edges per block   (E = 1,000,000 divisible by 32)
#define MV  32    // variables per block (V = 200,000 divisible by 32)

__device__ __forceinline__ float logsig(float x) {
    return fminf(x, 0.f) - __logf(1.f + __expf(-fabsf(x)));
}
// f32 -> bf16 RNE (bit trick; inputs are finite)
__device__ __forceinline__ u16 f2b(float f) {
    union { float f; unsigned u; } x; x.f = f;
    unsigned r = x.u + 0x7fffu + ((x.u >> 16) & 1u);
    return (u16)(r >> 16);
}
__device__ __forceinline__ ushort4 f2b4(float4 v) {
    ushort4 o; o.x = f2b(v.x); o.y = f2b(v.y); o.z = f2b(v.z); o.w = f2b(v.w);
    return o;
}
__device__ __forceinline__ bf16x8 ld_bf8(const short* p) {
    return __builtin_bit_cast(bf16x8, *(const short8*)p);
}

// ---------------------------------------------------------------------------
// Weight pre-conversion f32 -> bf16 in workspace. W1m rows padded 145 -> 160.
// ---------------------------------------------------------------------------
__global__ __launch_bounds__(256) void conv_weights(
    const float* __restrict__ W1m, const float* __restrict__ W2m,
    const float* __restrict__ W1a, const float* __restrict__ W2a,
    short* __restrict__ W1mb, short* __restrict__ W2mb,
    short* __restrict__ W1ab, short* __restrict__ W2ab)
{
    int i = blockIdx.x * 256 + threadIdx.x;
    if (i < 256 * K1) {                              // W1mb [256][160]
        int n = i / K1, k = i - n * K1;
        W1mb[i] = (k < DIN) ? (short)f2b(W1m[n * DIN + k]) : (short)0;
    } else if (i < 256 * K1 + 256 * HQ) {            // W2mb [256][256]
        int j = i - 256 * K1;
        W2mb[j] = (short)f2b(W2m[j]);
    } else if (i < 256 * K1 + 2 * 256 * HQ) {        // W1ab [256][256]
        int j = i - 256 * K1 - 256 * HQ;
        W1ab[j] = (short)f2b(W1a[j]);
    } else if (i < 256 * K1 + 2 * 256 * HQ + 128 * HQ) { // W2ab [128][256]
        int j = i - 256 * K1 - 2 * 256 * HQ;
        W2ab[j] = (short)f2b(W2a[j]);
    }
}

// ---------------------------------------------------------------------------
// Edge stage (MFMA): 32-edge tile, 4 waves, wave w owns hidden cols w*64..+63.
// LDS = 27.8 KB -> 5 blocks/CU (20 waves/CU) for latency hiding.
// mfma_f32_32x32x16_bf16: A[m=lane&31][k=(lane>>5)*8+j];
// D: col=lane&31, row=(reg&3)+8*(reg>>2)+4*(lane>>5).
// ---------------------------------------------------------------------------
__global__ __launch_bounds__(256) void edge_mfma(
    const float* __restrict__ vs, const float* __restrict__ ef,
    const float* __restrict__ sol, const float* __restrict__ b1m,
    const short* __restrict__ W1mb, const short* __restrict__ W2mb,
    const int* __restrict__ vidx, const int* __restrict__ esign,
    float* __restrict__ agg, int E)
{
    __shared__ short xs[ME][K1P];    // 10752 B
    __shared__ short h1s[ME][HQP];   // 16896 B
    __shared__ int   vix[ME];        //   128 B  -> 27776 B total
    const int tid = threadIdx.x;
    const int e0 = blockIdx.x * ME;

    // ---- gather: vs rows (32 x 32 float4) ----
    for (int i = tid; i < ME * 32; i += 256) {
        int e = i >> 5, q = (i & 31) << 2;
        float4 v = *(const float4*)&vs[(size_t)(e0 + e) * DD + q];
        *(ushort4*)&xs[e][q] = f2b4(v);
    }
    // ---- ef (32 x 4 float4) ----
    if (tid < ME * 4) {
        int e = tid >> 2, q = (tid & 3) << 2;
        float4 v = *(const float4*)&ef[(size_t)(e0 + e) * FE + q];
        *(ushort4*)&xs[e][DD + q] = f2b4(v);
    }
    // ---- signed solution column + K-pad + vidx ----
    for (int i = tid; i < ME * 16; i += 256) {
        int e = i >> 4, k = i & 15;
        if (k == 0) {
            int gi = vidx[e0 + e];
            vix[e] = gi;
            xs[e][144] = (short)f2b((float)esign[e0 + e] * sol[gi]);
        } else {
            xs[e][144 + k] = 0;
        }
    }
    __syncthreads();

    const int wv = tid >> 6, lane = tid & 63;
    const int lr = lane & 31, lh = lane >> 5;
    const int n0 = wv * 64;

    // ---- layer 1: [32 x 160] @ [160 x 64-chunk] ----
    floatx16 a0 = {}, a1 = {};
    #pragma unroll
    for (int ks = 0; ks < K1 / 16; ++ks) {
        int k = ks * 16 + lh * 8;
        bf16x8 A  = ld_bf8(&xs[lr][k]);
        bf16x8 B0 = ld_bf8(&W1mb[(size_t)(n0 + lr) * K1 + k]);
        bf16x8 B1 = ld_bf8(&W1mb[(size_t)(n0 + 32 + lr) * K1 + k]);
        a0 = __builtin_amdgcn_mfma_f32_32x32x16_bf16(A, B0, a0, 0, 0, 0);
        a1 = __builtin_amdgcn_mfma_f32_32x32x16_bf16(A, B1, a1, 0, 0, 0);
    }
    {
        float bn0 = b1m[n0 + lr], bn1 = b1m[n0 + 32 + lr];
        #pragma unroll
        for (int r = 0; r < 16; ++r) {
            int row = (r & 3) + 8 * (r >> 2) + 4 * lh;
            h1s[row][n0 + lr]      = (short)f2b(logsig(a0[r] + bn0));
            h1s[row][n0 + 32 + lr] = (short)f2b(logsig(a1[r] + bn1));
        }
    }
    __syncthreads();

    // ---- layer 2: [32 x 256] @ [256 x 64-chunk] ----
    a0 = (floatx16){}; a1 = (floatx16){};
    #pragma unroll
    for (int ks = 0; ks < HQ / 16; ++ks) {
        int k = ks * 16 + lh * 8;
        bf16x8 A  = ld_bf8(&h1s[lr][k]);
        bf16x8 B0 = ld_bf8(&W2mb[(size_t)(n0 + lr) * HQ + k]);
        bf16x8 B1 = ld_bf8(&W2mb[(size_t)(n0 + 32 + lr) * HQ + k]);
        a0 = __builtin_amdgcn_mfma_f32_32x32x16_bf16(A, B0, a0, 0, 0, 0);
        a1 = __builtin_amdgcn_mfma_f32_32x32x16_bf16(A, B1, a1, 0, 0, 0);
    }
    // ---- epilogue: logsig + coalesced f32 atomics into agg ----
    #pragma unroll
    for (int r = 0; r < 16; ++r) {
        int row = (r & 3) + 8 * (r >> 2) + 4 * lh;
        int va = vix[row];
        atomicAdd(&agg[(size_t)va * HQ + n0 + lr],      logsig(a0[r]));
        atomicAdd(&agg[(size_t)va * HQ + n0 + 32 + lr], logsig(a1[r]));
    }
}

// ---------------------------------------------------------------------------
// Variable stage (MFMA): h = ls(ls(agg@W1a^T+b1a)@W2a^T); out = h@Wc^T + bc
// 32-var tile, 4 waves. LDS 33.8 KB -> 4 blocks/CU. Classifier uses all 256
// threads (4 lanes per output, shuffle-reduced).
// ---------------------------------------------------------------------------
__global__ __launch_bounds__(256) void var_mfma(
    const float* __restrict__ agg, const float* __restrict__ b1a,
    const short* __restrict__ W1ab, const short* __restrict__ W2ab,
    const float* __restrict__ Wc, const float* __restrict__ bc,
    float* __restrict__ out, int V)
{
    __shared__ short as_s[MV][HQP];     // 16896 B
    __shared__ short h1v[MV][HQP];      // 16896 B
    const int tid = threadIdx.x;
    const int v0 = blockIdx.x * MV;

    // ---- load agg tile (32 x 64 float4), convert to bf16 ----
    for (int i = tid; i < MV * 64; i += 256) {
        int v = i >> 6, q = (i & 63) << 2;
        float4 a = *(const float4*)&agg[(size_t)(v0 + v) * HQ + q];
        *(ushort4*)&as_s[v][q] = f2b4(a);
    }
    __syncthreads();

    const int wv = tid >> 6, lane = tid & 63;
    const int lr = lane & 31, lh = lane >> 5;
    const int n0 = wv * 64;

    // ---- layer 1: M=32, N=64/wave, K=256 ----
    floatx16 c0 = {}, c1 = {};
    #pragma unroll
    for (int ks = 0; ks < HQ / 16; ++ks) {
        int k = ks * 16 + lh * 8;
        bf16x8 A  = ld_bf8(&as_s[lr][k]);
        bf16x8 B0 = ld_bf8(&W1ab[(size_t)(n0 + lr) * HQ + k]);
        bf16x8 B1 = ld_bf8(&W1ab[(size_t)(n0 + 32 + lr) * HQ + k]);
        c0 = __builtin_amdgcn_mfma_f32_32x32x16_bf16(A, B0, c0, 0, 0, 0);
        c1 = __builtin_amdgcn_mfma_f32_32x32x16_bf16(A, B1, c1, 0, 0, 0);
    }
    {
        float bn0 = b1a[n0 + lr], bn1 = b1a[n0 + 32 + lr];
        #pragma unroll
        for (int r = 0; r < 16; ++r) {
            int row = (r & 3) + 8 * (r >> 2) + 4 * lh;
            h1v[row][n0 + lr]      = (short)f2b(logsig(c0[r] + bn0));
            h1v[row][n0 + 32 + lr] = (short)f2b(logsig(c1[r] + bn1));
        }
    }
    __syncthreads();

    // ---- layer 2: M=32, N=32/wave, K=256; h (bf16) overwrites as_s ----
    floatx16 d0 = {};
    const int n0b = wv * 32;
    #pragma unroll
    for (int ks = 0; ks < HQ / 16; ++ks) {
        int k = ks * 16 + lh * 8;
        bf16x8 A = ld_bf8(&h1v[lr][k]);
        bf16x8 B = ld_bf8(&W2ab[(size_t)(n0b + lr) * HQ + k]);
        d0 = __builtin_amdgcn_mfma_f32_32x32x16_bf16(A, B, d0, 0, 0, 0);
    }
    __syncthreads();   // everyone done reading as_s (layer1 A) before overwrite
    #pragma unroll
    for (int r = 0; r < 16; ++r) {
        int row = (r & 3) + 8 * (r >> 2) + 4 * lh;
        as_s[row][n0b + lr] = (short)f2b(logsig(d0[r]));
    }
    __syncthreads();

    // ---- classifier: 64 outputs (32 v x 2 p), 4 lanes each, shfl reduce ----
    {
        int oid = tid >> 2;          // 0..63
        int part = tid & 3;          // 0..3
        int v = oid >> 1, p = oid & 1;
        const float* wrow = Wc + (size_t)p * DD + part * 32;
        const short* hrow = &as_s[v][part * 32];
        float acc = 0.f;
        #pragma unroll
        for (int k = 0; k < 32; k += 8) {
            bf16x8 h8 = ld_bf8(&hrow[k]);
            #pragma unroll
            for (int j = 0; j < 8; ++j)
                acc = fmaf((float)h8[j], wrow[k + j], acc);
        }
        acc += __shfl_down(acc, 1);
        acc += __shfl_down(acc, 2);
        if (part == 0) out[(size_t)(v0 + v) * 2 + p] = acc + bc[p];
    }
}

extern "C" void kernel_launch(void* const* d_in, const int* in_sizes, int n_in,
                              void* d_out, int out_size, void* d_ws, size_t ws_size,
                              hipStream_t stream) {
    const float* vs  = (const float*)d_in[0];   // [E,128] f32
    const float* ef  = (const float*)d_in[1];   // [E,16]
    const float* sol = (const float*)d_in[2];   // [V]
    const float* W1m = (const float*)d_in[3];   // [256,145]
    const float* b1m = (const float*)d_in[4];   // [256]
    const float* W2m = (const float*)d_in[5];   // [256,256]
    const float* W1a = (const float*)d_in[6];   // [256,256]
    const float* b1a = (const float*)d_in[7];   // [256]
    const float* W2a = (const float*)d_in[8];   // [128,256]
    const float* Wc  = (const float*)d_in[9];   // [2,128]
    const float* bc  = (const float*)d_in[10];  // [2]
    const int* vidx  = (const int*)d_in[11];    // [E]
    const int* sgn   = (const int*)d_in[12];    // [E]

    const int E = in_sizes[0] / DD;   // 1,000,000
    const int V = in_sizes[2];        //   200,000

    char* ws = (char*)d_ws;
    float* agg = (float*)ws;                          // [V,256] f32 = 204.8 MB
    size_t off = (size_t)V * HQ * sizeof(float);
    short* W1mb = (short*)(ws + off); off += (size_t)256 * K1 * 2;
    short* W2mb = (short*)(ws + off); off += (size_t)256 * HQ * 2;
    short* W1ab = (short*)(ws + off); off += (size_t)256 * HQ * 2;
    short* W2ab = (short*)(ws + off);

    hipMemsetAsync(agg, 0, (size_t)V * HQ * sizeof(float), stream);
    conv_weights<<<dim3(800), dim3(256), 0, stream>>>(
        W1m, W2m, W1a, W2a, W1mb, W2mb, W1ab, W2ab);
    edge_mfma<<<dim3(E / ME), dim3(256), 0, stream>>>(
        vs, ef, sol, b1m, W1mb, W2mb, vidx, sgn, agg, E);
    var_mfma<<<dim3(V / MV), dim3(256), 0, stream>>>(
        agg, b1a, W1ab, W2ab, Wc, bc, (float*)d_out, V);
}